// Round 1
// baseline (713.740 us; speedup 1.0000x reference)
//
#include <hip/hip_runtime.h>
#include <math.h>

// ---------------- wave helpers (wave = 64 lanes) ----------------
__device__ __forceinline__ float wsum64(float v){
  #pragma unroll
  for (int off = 32; off > 0; off >>= 1) v += __shfl_xor(v, off, 64);
  return v;
}
__device__ __forceinline__ float wmax64(float v){
  #pragma unroll
  for (int off = 32; off > 0; off >>= 1) v = fmaxf(v, __shfl_xor(v, off, 64));
  return v;
}

// ---------------- tiny precompute kernels ----------------
// kq[h*128+c] = sum_d K[h,c,d] * Q[h,d]    (K: [4][128][32], Q: [4][32])
__global__ void kq_kernel(const float* __restrict__ K, const float* __restrict__ Q,
                          float* __restrict__ kq){
  int i = blockIdx.x * blockDim.x + threadIdx.x;
  if (i >= 512) return;
  int h = i >> 7, c = i & 127;
  const float* Kp = K + (size_t)h * 4096 + (size_t)c * 32;
  const float* Qp = Q + h * 32;
  float s = 0.f;
  #pragma unroll
  for (int d = 0; d < 32; ++d) s += Kp[d] * Qp[d];
  kq[i] = s;
}

// Vt[c*128 + h*32 + d] = V[h*4096 + c*32 + d]
__global__ void vt_kernel(const float* __restrict__ V, float* __restrict__ Vt){
  int o = blockIdx.x * blockDim.x + threadIdx.x;
  if (o >= 16384) return;
  int c = o >> 7, hd = o & 127;
  int h = hd >> 5, d = hd & 31;
  Vt[o] = V[(size_t)h * 4096 + (size_t)c * 32 + d];
}

// logits[r*4+h] = x[r]·kq[h]   (one wave per row)
__global__ __launch_bounds__(256) void logits_kernel(const float* __restrict__ x,
                                                     const float* __restrict__ kq,
                                                     float* __restrict__ logits, int R){
  int row = (blockIdx.x << 2) + (threadIdx.x >> 6);
  if (row >= R) return;
  int lane = threadIdx.x & 63;
  float x1 = x[128 * (size_t)row + lane];
  float x2 = x[128 * (size_t)row + lane + 64];
  float p0 = x1 * kq[lane]       + x2 * kq[lane + 64];
  float p1 = x1 * kq[128 + lane] + x2 * kq[192 + lane];
  float p2 = x1 * kq[256 + lane] + x2 * kq[320 + lane];
  float p3 = x1 * kq[384 + lane] + x2 * kq[448 + lane];
  p0 = wsum64(p0); p1 = wsum64(p1); p2 = wsum64(p2); p3 = wsum64(p3);
  if (lane == 0) *(float4*)(logits + 4 * (size_t)row) = make_float4(p0, p1, p2, p3);
}

// ---------------- CSR build ----------------
__global__ void hist_kernel(const int* __restrict__ tgt, int* __restrict__ cnt, int E){
  int e = blockIdx.x * blockDim.x + threadIdx.x;
  if (e < E) atomicAdd(&cnt[tgt[e]], 1);
}

__global__ __launch_bounds__(1024) void scan_kernel(const int* __restrict__ cnt,
                                                    int* __restrict__ rowptr, int n){
  __shared__ int wsum[16];
  int tid = threadIdx.x, lane = tid & 63, wv = tid >> 6;
  int carry = 0;
  for (int base = 0; base < n; base += 1024){
    int i = base + tid;
    int v = (i < n) ? cnt[i] : 0;
    int s = v;
    #pragma unroll
    for (int off = 1; off < 64; off <<= 1){
      int t = __shfl_up(s, off, 64);
      if (lane >= off) s += t;
    }
    if (lane == 63) wsum[wv] = s;
    __syncthreads();
    if (wv == 0 && lane < 16){
      int t = wsum[lane];
      #pragma unroll
      for (int off = 1; off < 16; off <<= 1){
        int u = __shfl_up(t, off, 64);
        if (lane >= off) t += u;
      }
      wsum[lane] = t;
    }
    __syncthreads();
    int woff  = (wv == 0) ? 0 : wsum[wv - 1];
    int total = wsum[15];
    if (i < n) rowptr[i] = carry + s + woff - v;   // exclusive
    __syncthreads();
    carry += total;
  }
  if (tid == 0) rowptr[n] = carry;
}

__global__ void scatter_kernel(const int* __restrict__ tgt, const int* __restrict__ src,
                               const int* __restrict__ rowptr, int* __restrict__ fill,
                               int* __restrict__ col, int E){
  int e = blockIdx.x * blockDim.x + threadIdx.x;
  if (e >= E) return;
  int t = tgt[e];
  int pos = atomicAdd(&fill[t], 1);
  col[rowptr[t] + pos] = src[e];
}

// ---------------- softmax-aggregate + (+Qw) + LN0 : one wave per target ----------------
__global__ __launch_bounds__(256) void agg_kernel(const int* __restrict__ rowptr,
                                                  const int* __restrict__ col,
                                                  const float* __restrict__ logits,
                                                  const float* __restrict__ xV,
                                                  const float* __restrict__ qvec,
                                                  const float* __restrict__ g0,
                                                  const float* __restrict__ b0,
                                                  float* __restrict__ h_out, int n_tgt){
  int wid = (blockIdx.x << 2) + (threadIdx.x >> 6);
  if (wid >= n_tgt) return;
  int lane = threadIdx.x & 63;
  int head = lane >> 4;                 // lane owns dims 2*lane, 2*lane+1 -> head = lane/16
  int beg = rowptr[wid];
  int k   = rowptr[wid + 1] - beg;

  // phase 1: per-head max over the segment
  float mx0 = -INFINITY, mx1 = -INFINITY, mx2 = -INFINITY, mx3 = -INFINITY;
  for (int i = lane; i < k; i += 64){
    int s = col[beg + i];
    float4 a = *(const float4*)(logits + 4 * (size_t)s);
    mx0 = fmaxf(mx0, a.x); mx1 = fmaxf(mx1, a.y);
    mx2 = fmaxf(mx2, a.z); mx3 = fmaxf(mx3, a.w);
  }
  mx0 = wmax64(mx0); mx1 = wmax64(mx1); mx2 = wmax64(mx2); mx3 = wmax64(mx3);
  float mymax = (head == 0) ? mx0 : (head == 1) ? mx1 : (head == 2) ? mx2 : mx3;

  // phase 2: sequential edges; every lane recomputes w for its own head (denom falls out free)
  float accx = 0.f, accy = 0.f, sumw = 0.f;
  #pragma unroll 4
  for (int e = 0; e < k; ++e){
    int se = col[beg + e];                                  // wave-uniform
    float a = logits[4 * (size_t)se + head];                // one 16B line per wave
    float w = __expf(a - mymax);
    sumw += w;
    float2 v = *(const float2*)(xV + 128 * (size_t)se + 2 * lane);  // coalesced 512B row
    accx += w * v.x; accy += w * v.y;
  }
  float inv = (k > 0) ? 1.f / sumw : 0.f;
  accx *= inv; accy *= inv;

  // + Qw broadcast
  float2 q = *(const float2*)(qvec + 2 * lane);
  accx += q.x; accy += q.y;

  // LayerNorm over 128 dims
  float mean = wsum64(accx + accy) * (1.f / 128.f);
  float dx = accx - mean, dy = accy - mean;
  float var = wsum64(dx * dx + dy * dy) * (1.f / 128.f);
  float rstd = rsqrtf(var + 1e-5f);
  float2 g = *(const float2*)(g0 + 2 * lane);
  float2 b = *(const float2*)(b0 + 2 * lane);
  float2 o;
  o.x = dx * rstd * g.x + b.x;
  o.y = dy * rstd * g.y + b.y;
  *(float2*)(h_out + 128 * (size_t)wid + 2 * lane) = o;
}

// ---------------- fp32 tiled GEMM: C[R,128] = act(A[R,128] @ B[128,128]) ----------------
__global__ __launch_bounds__(256) void gemm128_kernel(const float* __restrict__ A,
                                                      const float* __restrict__ B,
                                                      float* __restrict__ C, int R, int do_relu){
  __shared__ float As[64][36];    // +4 pad keeps 16B alignment
  __shared__ float Bs[32][132];
  int tid = threadIdx.x;
  int tx = tid & 31;              // 4 cols each
  int ty = tid >> 5;              // 8 rows each
  int row0 = blockIdx.x * 64;
  float acc[8][4];
  #pragma unroll
  for (int r = 0; r < 8; ++r){ acc[r][0]=0.f; acc[r][1]=0.f; acc[r][2]=0.f; acc[r][3]=0.f; }

  for (int k0 = 0; k0 < 128; k0 += 32){
    #pragma unroll
    for (int i = 0; i < 2; ++i){
      int f4 = tid * 2 + i;
      int r = f4 >> 3, kk4 = f4 & 7;
      float4 val = make_float4(0.f, 0.f, 0.f, 0.f);
      int gr = row0 + r;
      if (gr < R) val = *(const float4*)(A + 128 * (size_t)gr + k0 + kk4 * 4);
      *(float4*)&As[r][kk4 * 4] = val;
    }
    #pragma unroll
    for (int i = 0; i < 4; ++i){
      int f4 = tid + i * 256;
      int r = f4 >> 5, c4 = f4 & 31;
      *(float4*)&Bs[r][c4 * 4] = *(const float4*)(B + 128 * (size_t)(k0 + r) + c4 * 4);
    }
    __syncthreads();
    #pragma unroll
    for (int kk = 0; kk < 32; ++kk){
      float4 b = *(const float4*)&Bs[kk][tx * 4];
      #pragma unroll
      for (int rr = 0; rr < 8; ++rr){
        float a = As[ty * 8 + rr][kk];
        acc[rr][0] += a * b.x; acc[rr][1] += a * b.y;
        acc[rr][2] += a * b.z; acc[rr][3] += a * b.w;
      }
    }
    __syncthreads();
  }
  #pragma unroll
  for (int rr = 0; rr < 8; ++rr){
    int gr = row0 + ty * 8 + rr;
    if (gr < R){
      float4 v = make_float4(acc[rr][0], acc[rr][1], acc[rr][2], acc[rr][3]);
      if (do_relu){
        v.x = fmaxf(v.x, 0.f); v.y = fmaxf(v.y, 0.f);
        v.z = fmaxf(v.z, 0.f); v.w = fmaxf(v.w, 0.f);
      }
      *(float4*)(C + 128 * (size_t)gr + tx * 4) = v;
    }
  }
}

// ---------------- out = relu(LN(h + m)) : one wave per row ----------------
__global__ __launch_bounds__(256) void final_ln_kernel(const float* __restrict__ h,
                                                       const float* __restrict__ m,
                                                       const float* __restrict__ g,
                                                       const float* __restrict__ b,
                                                       float* __restrict__ out, int R){
  int row = (blockIdx.x << 2) + (threadIdx.x >> 6);
  if (row >= R) return;
  int lane = threadIdx.x & 63;
  float2 hv = *(const float2*)(h + 128 * (size_t)row + 2 * lane);
  float2 mv = *(const float2*)(m + 128 * (size_t)row + 2 * lane);
  float vx = hv.x + mv.x, vy = hv.y + mv.y;
  float mean = wsum64(vx + vy) * (1.f / 128.f);
  float dx = vx - mean, dy = vy - mean;
  float var = wsum64(dx * dx + dy * dy) * (1.f / 128.f);
  float rstd = rsqrtf(var + 1e-5f);
  float2 gg = *(const float2*)(g + 2 * lane);
  float2 bb = *(const float2*)(b + 2 * lane);
  float ox = fmaxf(dx * rstd * gg.x + bb.x, 0.f);
  float oy = fmaxf(dy * rstd * gg.y + bb.y, 0.f);
  *(float2*)(out + 128 * (size_t)row + 2 * lane) = make_float2(ox, oy);
}

// ---------------- host side ----------------
struct Ws {
  float *kq, *Vt, *logits, *xv, *h, *m;
  int *rowptr, *cnt, *fill, *col;
};

static void run_stage(const float* x, int R_src,
                      const int* tgt, const int* src, int n_tgt, int E,
                      const float* K, const float* Qw, const float* V,
                      const float* g0, const float* b0,
                      const float* W1, const float* W2,
                      const float* g1, const float* b1,
                      float* out, const Ws& ws, hipStream_t stream)
{
  kq_kernel<<<1, 512, 0, stream>>>(K, Qw, ws.kq);
  vt_kernel<<<64, 256, 0, stream>>>(V, ws.Vt);
  logits_kernel<<<(R_src + 3) / 4, 256, 0, stream>>>(x, ws.kq, ws.logits, R_src);
  gemm128_kernel<<<(R_src + 63) / 64, 256, 0, stream>>>(x, ws.Vt, ws.xv, R_src, 0);

  hipMemsetAsync(ws.cnt, 0, (size_t)n_tgt * sizeof(int), stream);
  hipMemsetAsync(ws.fill, 0, (size_t)n_tgt * sizeof(int), stream);
  hist_kernel<<<(E + 255) / 256, 256, 0, stream>>>(tgt, ws.cnt, E);
  scan_kernel<<<1, 1024, 0, stream>>>(ws.cnt, ws.rowptr, n_tgt);
  scatter_kernel<<<(E + 255) / 256, 256, 0, stream>>>(tgt, src, ws.rowptr, ws.fill, ws.col, E);

  agg_kernel<<<(n_tgt + 3) / 4, 256, 0, stream>>>(ws.rowptr, ws.col, ws.logits, ws.xv,
                                                  Qw, g0, b0, ws.h, n_tgt);
  // MLP: t = relu(h@W1) (t aliases xv — xv dead after agg), m = relu(t@W2)
  gemm128_kernel<<<(n_tgt + 63) / 64, 256, 0, stream>>>(ws.h, W1, ws.xv, n_tgt, 1);
  gemm128_kernel<<<(n_tgt + 63) / 64, 256, 0, stream>>>(ws.xv, W2, ws.m, n_tgt, 1);
  final_ln_kernel<<<(n_tgt + 3) / 4, 256, 0, stream>>>(ws.h, ws.m, g1, b1, out, n_tgt);
}

extern "C" void kernel_launch(void* const* d_in, const int* in_sizes, int n_in,
                              void* d_out, int out_size, void* d_ws, size_t ws_size,
                              hipStream_t stream)
{
  const float* x0        = (const float*)d_in[0];
  const int*   node_idx  = (const int*)d_in[1];
  const int*   hedge_idx = (const int*)d_in[2];
  const float* v2e_K = (const float*)d_in[5];
  const float* v2e_Q = (const float*)d_in[6];
  const float* v2e_V = (const float*)d_in[7];
  const float* v2e_g0 = (const float*)d_in[8];
  const float* v2e_b0 = (const float*)d_in[9];
  const float* v2e_W1 = (const float*)d_in[10];
  const float* v2e_W2 = (const float*)d_in[11];
  const float* v2e_g1 = (const float*)d_in[12];
  const float* v2e_b1 = (const float*)d_in[13];
  const float* e2v_K = (const float*)d_in[14];
  const float* e2v_Q = (const float*)d_in[15];
  const float* e2v_V = (const float*)d_in[16];
  const float* e2v_g0 = (const float*)d_in[17];
  const float* e2v_b0 = (const float*)d_in[18];
  const float* e2v_W1 = (const float*)d_in[19];
  const float* e2v_W2 = (const float*)d_in[20];
  const float* e2v_g1 = (const float*)d_in[21];
  const float* e2v_b1 = (const float*)d_in[22];

  int N = in_sizes[0] / 128;          // 50000
  int E = in_sizes[1];                // 1000000
  int M = out_size / 128 - N;         // 20000

  float* out_x0 = (float*)d_out;                       // [N,128]
  float* out_x1 = (float*)d_out + (size_t)N * 128;     // [M,128]

  // workspace carve-up (max dims: rows<=N, edges=E)
  size_t off = 0;
  char* base = (char*)d_ws;
  auto alloc = [&](size_t bytes) -> void* {
    void* p = base + off;
    off += (bytes + 255) & ~(size_t)255;
    return p;
  };
  Ws ws;
  ws.kq     = (float*)alloc(512 * 4);
  ws.Vt     = (float*)alloc(16384 * 4);
  ws.logits = (float*)alloc((size_t)N * 4 * 4);
  ws.xv     = (float*)alloc((size_t)N * 128 * 4);
  ws.h      = (float*)alloc((size_t)N * 128 * 4);
  ws.m      = (float*)alloc((size_t)N * 128 * 4);
  ws.rowptr = (int*)alloc(((size_t)N + 1) * 4);
  ws.cnt    = (int*)alloc((size_t)N * 4);
  ws.fill   = (int*)alloc((size_t)N * 4);
  ws.col    = (int*)alloc((size_t)E * 4);
  (void)ws_size; (void)n_in;

  // stage 1: vertex -> hyperedge  (tgt = hedge_idx, src = node_idx), out = x_1
  run_stage(x0, N, hedge_idx, node_idx, M, E,
            v2e_K, v2e_Q, v2e_V, v2e_g0, v2e_b0, v2e_W1, v2e_W2, v2e_g1, v2e_b1,
            out_x1, ws, stream);

  // stage 2: hyperedge -> vertex  (tgt = node_idx, src = hedge_idx), out = x_0_out
  run_stage(out_x1, M, node_idx, hedge_idx, N, E,
            e2v_K, e2v_Q, e2v_V, e2v_g0, e2v_b0, e2v_W1, e2v_W2, e2v_g1, e2v_b1,
            out_x0, ws, stream);
}

// Round 2
// 596.565 us; speedup vs baseline: 1.1964x; 1.1964x over previous
//
#include <hip/hip_runtime.h>
#include <math.h>

typedef __attribute__((ext_vector_type(8))) short bf16x8;
typedef __attribute__((ext_vector_type(4))) float f32x4;

// ---------------- bf16 helpers ----------------
__device__ __forceinline__ unsigned short f2bf(float f){
  union { float f; unsigned int u; } c; c.f = f;
  unsigned int u = c.u;
  u += 0x7fff + ((u >> 16) & 1);          // RNE
  return (unsigned short)(u >> 16);
}
__device__ __forceinline__ float bf2f(unsigned short h){
  union { unsigned int u; float f; } c; c.u = ((unsigned int)h) << 16;
  return c.f;
}

// ---------------- wave helpers (wave = 64 lanes) ----------------
__device__ __forceinline__ float wsum64(float v){
  #pragma unroll
  for (int off = 32; off > 0; off >>= 1) v += __shfl_xor(v, off, 64);
  return v;
}
__device__ __forceinline__ float wmax64(float v){
  #pragma unroll
  for (int off = 32; off > 0; off >>= 1) v = fmaxf(v, __shfl_xor(v, off, 64));
  return v;
}

// ---------------- tiny precompute kernels ----------------
// kq[h*128+c] = sum_d K[h,c,d] * Q[h,d]    (K: [4][128][32], Q: [4][32])
__global__ void kq_kernel(const float* __restrict__ K, const float* __restrict__ Q,
                          float* __restrict__ kq){
  int i = blockIdx.x * blockDim.x + threadIdx.x;
  if (i >= 512) return;
  int h = i >> 7, c = i & 127;
  const float* Kp = K + (size_t)h * 4096 + (size_t)c * 32;
  const float* Qp = Q + h * 32;
  float s = 0.f;
  #pragma unroll
  for (int d = 0; d < 32; ++d) s += Kp[d] * Qp[d];
  kq[i] = s;
}

// Bt[(h*32+d)*128 + c] = bf16(V[h*4096 + c*32 + d])   (B^T layout [n][k] for MFMA)
__global__ void btv_kernel(const float* __restrict__ V, unsigned short* __restrict__ Bt){
  int o = blockIdx.x * blockDim.x + threadIdx.x;
  if (o >= 16384) return;
  int n = o >> 7, k = o & 127;
  int h = n >> 5, d = n & 31;
  Bt[o] = f2bf(V[(size_t)h * 4096 + (size_t)k * 32 + d]);
}

// Bt[n*128+k] = bf16(W[k*128+n])
__global__ void btw_kernel(const float* __restrict__ W, unsigned short* __restrict__ Bt){
  int o = blockIdx.x * blockDim.x + threadIdx.x;
  if (o >= 16384) return;
  int n = o >> 7, k = o & 127;
  Bt[o] = f2bf(W[(size_t)k * 128 + n]);
}

// logits[r*4+h] = x[r]·kq[h]   (one wave per row)
__global__ __launch_bounds__(256) void logits_kernel(const float* __restrict__ x,
                                                     const float* __restrict__ kq,
                                                     float* __restrict__ logits, int R){
  int row = (blockIdx.x << 2) + (threadIdx.x >> 6);
  if (row >= R) return;
  int lane = threadIdx.x & 63;
  float x1 = x[128 * (size_t)row + lane];
  float x2 = x[128 * (size_t)row + lane + 64];
  float p0 = x1 * kq[lane]       + x2 * kq[lane + 64];
  float p1 = x1 * kq[128 + lane] + x2 * kq[192 + lane];
  float p2 = x1 * kq[256 + lane] + x2 * kq[320 + lane];
  float p3 = x1 * kq[384 + lane] + x2 * kq[448 + lane];
  p0 = wsum64(p0); p1 = wsum64(p1); p2 = wsum64(p2); p3 = wsum64(p3);
  if (lane == 0) *(float4*)(logits + 4 * (size_t)row) = make_float4(p0, p1, p2, p3);
}

// ---------------- CSR build ----------------
__global__ void hist_kernel(const int* __restrict__ tgt, int* __restrict__ cnt, int E){
  int e = blockIdx.x * blockDim.x + threadIdx.x;
  if (e < E) atomicAdd(&cnt[tgt[e]], 1);
}

__global__ __launch_bounds__(1024) void scan_kernel(const int* __restrict__ cnt,
                                                    int* __restrict__ rowptr, int n){
  __shared__ int wsums[16];
  int tid = threadIdx.x, lane = tid & 63, wv = tid >> 6;
  int carry = 0;
  int nceil = (n + 4095) & ~4095;
  for (int base = 0; base < nceil; base += 4096){
    int i0 = base + tid * 4;
    int v0 = 0, v1 = 0, v2 = 0, v3 = 0;
    if (i0 + 3 < n){
      int4 v = *(const int4*)(cnt + i0);
      v0 = v.x; v1 = v.y; v2 = v.z; v3 = v.w;
    } else {
      if (i0     < n) v0 = cnt[i0];
      if (i0 + 1 < n) v1 = cnt[i0 + 1];
      if (i0 + 2 < n) v2 = cnt[i0 + 2];
      if (i0 + 3 < n) v3 = cnt[i0 + 3];
    }
    int tsum = v0 + v1 + v2 + v3;
    int s = tsum;
    #pragma unroll
    for (int off = 1; off < 64; off <<= 1){
      int t = __shfl_up(s, off, 64);
      if (lane >= off) s += t;
    }
    if (lane == 63) wsums[wv] = s;
    __syncthreads();
    if (wv == 0 && lane < 16){
      int t = wsums[lane];
      #pragma unroll
      for (int off = 1; off < 16; off <<= 1){
        int u = __shfl_up(t, off, 64);
        if (lane >= off) t += u;
      }
      wsums[lane] = t;
    }
    __syncthreads();
    int woff  = (wv == 0) ? 0 : wsums[wv - 1];
    int total = wsums[15];
    int excl = carry + woff + s - tsum;       // exclusive prefix of this thread's 4 elems
    if (i0 + 3 < n){
      int4 w;
      w.x = excl; w.y = excl + v0; w.z = excl + v0 + v1; w.w = excl + v0 + v1 + v2;
      *(int4*)(rowptr + i0) = w;
    } else {
      if (i0     < n) rowptr[i0]     = excl;
      if (i0 + 1 < n) rowptr[i0 + 1] = excl + v0;
      if (i0 + 2 < n) rowptr[i0 + 2] = excl + v0 + v1;
      if (i0 + 3 < n) rowptr[i0 + 3] = excl + v0 + v1 + v2;
    }
    __syncthreads();
    carry += total;
  }
  if (tid == 0) rowptr[n] = carry;
}

__global__ void scatter_kernel(const int* __restrict__ tgt, const int* __restrict__ src,
                               const int* __restrict__ rowptr, int* __restrict__ fill,
                               int* __restrict__ col, int E){
  int e = blockIdx.x * blockDim.x + threadIdx.x;
  if (e >= E) return;
  int t = tgt[e];
  int pos = atomicAdd(&fill[t], 1);
  col[rowptr[t] + pos] = src[e];
}

// ---------------- softmax-aggregate + (+Qw) + LN0 : one wave per target ----------------
// xV is bf16 [R_src,128]; writes h (fp32, residual) and hb (bf16, GEMM input)
__global__ __launch_bounds__(256) void agg_kernel(const int* __restrict__ rowptr,
                                                  const int* __restrict__ col,
                                                  const float* __restrict__ logits,
                                                  const unsigned short* __restrict__ xV,
                                                  const float* __restrict__ qvec,
                                                  const float* __restrict__ g0,
                                                  const float* __restrict__ b0,
                                                  float* __restrict__ h_out,
                                                  unsigned short* __restrict__ hb_out,
                                                  int n_tgt){
  int wid = (blockIdx.x << 2) + (threadIdx.x >> 6);
  if (wid >= n_tgt) return;
  int lane = threadIdx.x & 63;
  int head = lane >> 4;                 // lane owns dims 2*lane, 2*lane+1 -> head = lane/16
  int beg = rowptr[wid];
  int k   = rowptr[wid + 1] - beg;

  // phase 1: per-head max over the segment
  float mx0 = -INFINITY, mx1 = -INFINITY, mx2 = -INFINITY, mx3 = -INFINITY;
  for (int i = lane; i < k; i += 64){
    int s = col[beg + i];
    float4 a = *(const float4*)(logits + 4 * (size_t)s);
    mx0 = fmaxf(mx0, a.x); mx1 = fmaxf(mx1, a.y);
    mx2 = fmaxf(mx2, a.z); mx3 = fmaxf(mx3, a.w);
  }
  mx0 = wmax64(mx0); mx1 = wmax64(mx1); mx2 = wmax64(mx2); mx3 = wmax64(mx3);
  float mymax = (head == 0) ? mx0 : (head == 1) ? mx1 : (head == 2) ? mx2 : mx3;

  // phase 2: sequential edges; each lane recomputes w for its own head
  float accx = 0.f, accy = 0.f, sumw = 0.f;
  #pragma unroll 4
  for (int e = 0; e < k; ++e){
    int se = col[beg + e];                                  // wave-uniform
    float a = logits[4 * (size_t)se + head];                // one 16B line per wave
    float w = __expf(a - mymax);
    sumw += w;
    unsigned int v = *(const unsigned int*)(xV + 128 * (size_t)se + 2 * lane); // 4B coalesced
    accx += w * bf2f((unsigned short)(v & 0xffffu));
    accy += w * bf2f((unsigned short)(v >> 16));
  }
  float inv = (k > 0) ? 1.f / sumw : 0.f;
  accx *= inv; accy *= inv;

  // + Qw broadcast
  float2 q = *(const float2*)(qvec + 2 * lane);
  accx += q.x; accy += q.y;

  // LayerNorm over 128 dims
  float mean = wsum64(accx + accy) * (1.f / 128.f);
  float dx = accx - mean, dy = accy - mean;
  float var = wsum64(dx * dx + dy * dy) * (1.f / 128.f);
  float rstd = rsqrtf(var + 1e-5f);
  float2 g = *(const float2*)(g0 + 2 * lane);
  float2 b = *(const float2*)(b0 + 2 * lane);
  float ox = dx * rstd * g.x + b.x;
  float oy = dy * rstd * g.y + b.y;
  *(float2*)(h_out + 128 * (size_t)wid + 2 * lane) = make_float2(ox, oy);
  unsigned int pk = ((unsigned int)f2bf(oy) << 16) | (unsigned int)f2bf(ox);
  *(unsigned int*)(hb_out + 128 * (size_t)wid + 2 * lane) = pk;
}

// ---------------- bf16 MFMA GEMM: C[R,128] = act(A[R,128] @ B[128,128]) ----------------
// Bt is bf16 B^T [n][k]. 64 rows/block, 4 waves, full K=128 resident in LDS.
// A-frag: lane holds A[m=lane&15][k=quad*8+j]; B-frag: B[k=quad*8+j][n=lane&15];
// C/D: col=lane&15, row=quad*4+reg.
template<bool A_BF16, bool OUT_BF16, bool RELU>
__global__ __launch_bounds__(256) void mfma_gemm128(const void* __restrict__ Ap,
                                                    const unsigned short* __restrict__ Bt,
                                                    void* __restrict__ Cp, int R){
  __shared__ unsigned short As[64 * 136];    // row stride 136 (=272B, 16B-aligned, pad 8)
  __shared__ unsigned short Bs[128 * 136];
  int tid = threadIdx.x;
  int row0 = blockIdx.x * 64;

  // stage B^T (same for all blocks; L2-resident)
  #pragma unroll
  for (int i = 0; i < 16; ++i){
    int f = tid + i * 256;                   // ushort4 index
    int n = f >> 5, c4 = f & 31;
    *(ushort4*)&Bs[n * 136 + c4 * 4] = *(const ushort4*)(Bt + n * 128 + c4 * 4);
  }
  // stage A (convert fp32->bf16 if needed)
  if (A_BF16){
    const unsigned short* A = (const unsigned short*)Ap;
    #pragma unroll
    for (int i = 0; i < 8; ++i){
      int f = tid + i * 256;
      int r = f >> 5, c4 = f & 31;
      ushort4 v = make_ushort4(0, 0, 0, 0);
      if (row0 + r < R) v = *(const ushort4*)(A + (size_t)(row0 + r) * 128 + c4 * 4);
      *(ushort4*)&As[r * 136 + c4 * 4] = v;
    }
  } else {
    const float* A = (const float*)Ap;
    #pragma unroll
    for (int i = 0; i < 8; ++i){
      int f = tid + i * 256;
      int r = f >> 5, c4 = f & 31;
      float4 v = make_float4(0.f, 0.f, 0.f, 0.f);
      if (row0 + r < R) v = *(const float4*)(A + (size_t)(row0 + r) * 128 + c4 * 4);
      ushort4 h;
      h.x = f2bf(v.x); h.y = f2bf(v.y); h.z = f2bf(v.z); h.w = f2bf(v.w);
      *(ushort4*)&As[r * 136 + c4 * 4] = h;
    }
  }
  __syncthreads();

  int lane = tid & 63, wv = tid >> 6;
  int m = lane & 15, quad = lane >> 4;
  f32x4 acc[8];
  #pragma unroll
  for (int j = 0; j < 8; ++j) acc[j] = (f32x4){0.f, 0.f, 0.f, 0.f};

  #pragma unroll
  for (int q = 0; q < 4; ++q){
    bf16x8 a = *(const bf16x8*)&As[(wv * 16 + m) * 136 + q * 32 + quad * 8];
    #pragma unroll
    for (int j = 0; j < 8; ++j){
      bf16x8 b = *(const bf16x8*)&Bs[(j * 16 + m) * 136 + q * 32 + quad * 8];
      acc[j] = __builtin_amdgcn_mfma_f32_16x16x32_bf16(a, b, acc[j], 0, 0, 0);
    }
  }

  #pragma unroll
  for (int j = 0; j < 8; ++j){
    int colc = j * 16 + m;
    #pragma unroll
    for (int r = 0; r < 4; ++r){
      int gr = row0 + wv * 16 + quad * 4 + r;
      if (gr < R){
        float v = acc[j][r];
        if (RELU) v = fmaxf(v, 0.f);
        if (OUT_BF16) ((unsigned short*)Cp)[(size_t)gr * 128 + colc] = f2bf(v);
        else          ((float*)Cp)[(size_t)gr * 128 + colc] = v;
      }
    }
  }
}

// ---------------- out = relu(LN(h + m)) : one wave per row ----------------
__global__ __launch_bounds__(256) void final_ln_kernel(const float* __restrict__ h,
                                                       const float* __restrict__ m,
                                                       const float* __restrict__ g,
                                                       const float* __restrict__ b,
                                                       float* __restrict__ out, int R){
  int row = (blockIdx.x << 2) + (threadIdx.x >> 6);
  if (row >= R) return;
  int lane = threadIdx.x & 63;
  float2 hv = *(const float2*)(h + 128 * (size_t)row + 2 * lane);
  float2 mv = *(const float2*)(m + 128 * (size_t)row + 2 * lane);
  float vx = hv.x + mv.x, vy = hv.y + mv.y;
  float mean = wsum64(vx + vy) * (1.f / 128.f);
  float dx = vx - mean, dy = vy - mean;
  float var = wsum64(dx * dx + dy * dy) * (1.f / 128.f);
  float rstd = rsqrtf(var + 1e-5f);
  float2 gg = *(const float2*)(g + 2 * lane);
  float2 bb = *(const float2*)(b + 2 * lane);
  float ox = fmaxf(dx * rstd * gg.x + bb.x, 0.f);
  float oy = fmaxf(dy * rstd * gg.y + bb.y, 0.f);
  *(float2*)(out + 128 * (size_t)row + 2 * lane) = make_float2(ox, oy);
}

// ---------------- host side ----------------
struct Ws {
  float *kq, *logits, *h, *m;
  unsigned short *btV, *btW1, *btW2, *xv, *hb;   // bf16 buffers (xv doubles as MLP t)
  int *rowptr, *cnt, *fill, *col;
};

static void run_stage(const float* x, int R_src,
                      const int* tgt, const int* src, int n_tgt, int E,
                      const float* K, const float* Qw, const float* V,
                      const float* g0, const float* b0,
                      const float* W1, const float* W2,
                      const float* g1, const float* b1,
                      float* out, const Ws& ws, hipStream_t stream)
{
  kq_kernel<<<1, 512, 0, stream>>>(K, Qw, ws.kq);
  btv_kernel<<<64, 256, 0, stream>>>(V, ws.btV);
  btw_kernel<<<64, 256, 0, stream>>>(W1, ws.btW1);
  btw_kernel<<<64, 256, 0, stream>>>(W2, ws.btW2);
  logits_kernel<<<(R_src + 3) / 4, 256, 0, stream>>>(x, ws.kq, ws.logits, R_src);
  // xV = x @ V   (A fp32, out bf16)
  mfma_gemm128<false, true, false><<<(R_src + 63) / 64, 256, 0, stream>>>(x, ws.btV, ws.xv, R_src);

  hipMemsetAsync(ws.cnt, 0, (size_t)n_tgt * sizeof(int), stream);
  hipMemsetAsync(ws.fill, 0, (size_t)n_tgt * sizeof(int), stream);
  hist_kernel<<<(E + 255) / 256, 256, 0, stream>>>(tgt, ws.cnt, E);
  scan_kernel<<<1, 1024, 0, stream>>>(ws.cnt, ws.rowptr, n_tgt);
  scatter_kernel<<<(E + 255) / 256, 256, 0, stream>>>(tgt, src, ws.rowptr, ws.fill, ws.col, E);

  agg_kernel<<<(n_tgt + 3) / 4, 256, 0, stream>>>(ws.rowptr, ws.col, ws.logits, ws.xv,
                                                  Qw, g0, b0, ws.h, ws.hb, n_tgt);
  // MLP: t = relu(hb@W1) (bf16, aliases xv — xv dead after agg), m = relu(t@W2) fp32
  mfma_gemm128<true, true, true><<<(n_tgt + 63) / 64, 256, 0, stream>>>(ws.hb, ws.btW1, ws.xv, n_tgt);
  mfma_gemm128<true, false, true><<<(n_tgt + 63) / 64, 256, 0, stream>>>(ws.xv, ws.btW2, ws.m, n_tgt);
  final_ln_kernel<<<(n_tgt + 3) / 4, 256, 0, stream>>>(ws.h, ws.m, g1, b1, out, n_tgt);
}

extern "C" void kernel_launch(void* const* d_in, const int* in_sizes, int n_in,
                              void* d_out, int out_size, void* d_ws, size_t ws_size,
                              hipStream_t stream)
{
  const float* x0        = (const float*)d_in[0];
  const int*   node_idx  = (const int*)d_in[1];
  const int*   hedge_idx = (const int*)d_in[2];
  const float* v2e_K = (const float*)d_in[5];
  const float* v2e_Q = (const float*)d_in[6];
  const float* v2e_V = (const float*)d_in[7];
  const float* v2e_g0 = (const float*)d_in[8];
  const float* v2e_b0 = (const float*)d_in[9];
  const float* v2e_W1 = (const float*)d_in[10];
  const float* v2e_W2 = (const float*)d_in[11];
  const float* v2e_g1 = (const float*)d_in[12];
  const float* v2e_b1 = (const float*)d_in[13];
  const float* e2v_K = (const float*)d_in[14];
  const float* e2v_Q = (const float*)d_in[15];
  const float* e2v_V = (const float*)d_in[16];
  const float* e2v_g0 = (const float*)d_in[17];
  const float* e2v_b0 = (const float*)d_in[18];
  const float* e2v_W1 = (const float*)d_in[19];
  const float* e2v_W2 = (const float*)d_in[20];
  const float* e2v_g1 = (const float*)d_in[21];
  const float* e2v_b1 = (const float*)d_in[22];

  int N = in_sizes[0] / 128;          // 50000
  int E = in_sizes[1];                // 1000000
  int M = out_size / 128 - N;         // 20000

  float* out_x0 = (float*)d_out;                       // [N,128]
  float* out_x1 = (float*)d_out + (size_t)N * 128;     // [M,128]

  size_t off = 0;
  char* base = (char*)d_ws;
  auto alloc = [&](size_t bytes) -> void* {
    void* p = base + off;
    off += (bytes + 255) & ~(size_t)255;
    return p;
  };
  Ws ws;
  ws.kq     = (float*)alloc(512 * 4);
  ws.btV    = (unsigned short*)alloc(16384 * 2);
  ws.btW1   = (unsigned short*)alloc(16384 * 2);
  ws.btW2   = (unsigned short*)alloc(16384 * 2);
  ws.logits = (float*)alloc((size_t)N * 4 * 4);
  ws.xv     = (unsigned short*)alloc((size_t)N * 128 * 2);
  ws.hb     = (unsigned short*)alloc((size_t)N * 128 * 2);
  ws.h      = (float*)alloc((size_t)N * 128 * 4);
  ws.m      = (float*)alloc((size_t)N * 128 * 4);
  ws.rowptr = (int*)alloc(((size_t)N + 1) * 4);
  ws.cnt    = (int*)alloc((size_t)N * 4);
  ws.fill   = (int*)alloc((size_t)N * 4);
  ws.col    = (int*)alloc((size_t)E * 4);
  (void)ws_size; (void)n_in;

  // stage 1: vertex -> hyperedge  (tgt = hedge_idx, src = node_idx), out = x_1
  run_stage(x0, N, hedge_idx, node_idx, M, E,
            v2e_K, v2e_Q, v2e_V, v2e_g0, v2e_b0, v2e_W1, v2e_W2, v2e_g1, v2e_b1,
            out_x1, ws, stream);

  // stage 2: hyperedge -> vertex  (tgt = node_idx, src = hedge_idx), out = x_0_out
  run_stage(out_x1, M, node_idx, hedge_idx, N, E,
            e2v_K, e2v_Q, e2v_V, e2v_g0, e2v_b0, e2v_W1, e2v_W2, e2v_g1, e2v_b1,
            out_x0, ws, stream);
}

// Round 3
// 428.424 us; speedup vs baseline: 1.6660x; 1.3925x over previous
//
#include <hip/hip_runtime.h>
#include <math.h>

typedef __attribute__((ext_vector_type(8))) short bf16x8;
typedef __attribute__((ext_vector_type(4))) float f32x4;

// ---------------- bf16 helpers ----------------
__device__ __forceinline__ unsigned short f2bf(float f){
  union { float f; unsigned int u; } c; c.f = f;
  unsigned int u = c.u;
  u += 0x7fff + ((u >> 16) & 1);          // RNE
  return (unsigned short)(u >> 16);
}
__device__ __forceinline__ float bf2f(unsigned short h){
  union { unsigned int u; float f; } c; c.u = ((unsigned int)h) << 16;
  return c.f;
}

// ---------------- wave helpers (wave = 64 lanes) ----------------
__device__ __forceinline__ float wsum64(float v){
  #pragma unroll
  for (int off = 32; off > 0; off >>= 1) v += __shfl_xor(v, off, 64);
  return v;
}
__device__ __forceinline__ float wmax64(float v){
  #pragma unroll
  for (int off = 32; off > 0; off >>= 1) v = fmaxf(v, __shfl_xor(v, off, 64));
  return v;
}

// ---------------- tiny precompute kernels ----------------
__global__ void kq_kernel(const float* __restrict__ K, const float* __restrict__ Q,
                          float* __restrict__ kq){
  int i = blockIdx.x * blockDim.x + threadIdx.x;
  if (i >= 512) return;
  int h = i >> 7, c = i & 127;
  const float* Kp = K + (size_t)h * 4096 + (size_t)c * 32;
  const float* Qp = Q + h * 32;
  float s = 0.f;
  #pragma unroll
  for (int d = 0; d < 32; ++d) s += Kp[d] * Qp[d];
  kq[i] = s;
}

// Bt[(h*32+d)*128 + c] = bf16(V[h*4096 + c*32 + d])   (B^T layout [n][k] for MFMA)
__global__ void btv_kernel(const float* __restrict__ V, unsigned short* __restrict__ Bt){
  int o = blockIdx.x * blockDim.x + threadIdx.x;
  if (o >= 16384) return;
  int n = o >> 7, k = o & 127;
  int h = n >> 5, d = n & 31;
  Bt[o] = f2bf(V[(size_t)h * 4096 + (size_t)k * 32 + d]);
}

// Bt[n*128+k] = bf16(W[k*128+n])
__global__ void btw_kernel(const float* __restrict__ W, unsigned short* __restrict__ Bt){
  int o = blockIdx.x * blockDim.x + threadIdx.x;
  if (o >= 16384) return;
  int n = o >> 7, k = o & 127;
  Bt[o] = f2bf(W[(size_t)k * 128 + n]);
}

// logits[r*4+h] = x[r]·kq[h]   (one wave per row)
__global__ __launch_bounds__(256) void logits_kernel(const float* __restrict__ x,
                                                     const float* __restrict__ kq,
                                                     float* __restrict__ logits, int R){
  int row = (blockIdx.x << 2) + (threadIdx.x >> 6);
  if (row >= R) return;
  int lane = threadIdx.x & 63;
  float x1 = x[128 * (size_t)row + lane];
  float x2 = x[128 * (size_t)row + lane + 64];
  float p0 = x1 * kq[lane]       + x2 * kq[lane + 64];
  float p1 = x1 * kq[128 + lane] + x2 * kq[192 + lane];
  float p2 = x1 * kq[256 + lane] + x2 * kq[320 + lane];
  float p3 = x1 * kq[384 + lane] + x2 * kq[448 + lane];
  p0 = wsum64(p0); p1 = wsum64(p1); p2 = wsum64(p2); p3 = wsum64(p3);
  if (lane == 0) *(float4*)(logits + 4 * (size_t)row) = make_float4(p0, p1, p2, p3);
}

// ---------------- generic single-block exclusive scan (n elements + total at [n]) -------
__global__ __launch_bounds__(1024) void scan_kernel(const int* __restrict__ cnt,
                                                    int* __restrict__ rowptr, int n){
  __shared__ int wsums[16];
  int tid = threadIdx.x, lane = tid & 63, wv = tid >> 6;
  int carry = 0;
  int nceil = (n + 4095) & ~4095;
  for (int base = 0; base < nceil; base += 4096){
    int i0 = base + tid * 4;
    int v0 = 0, v1 = 0, v2 = 0, v3 = 0;
    if (i0 + 3 < n){
      int4 v = *(const int4*)(cnt + i0);
      v0 = v.x; v1 = v.y; v2 = v.z; v3 = v.w;
    } else {
      if (i0     < n) v0 = cnt[i0];
      if (i0 + 1 < n) v1 = cnt[i0 + 1];
      if (i0 + 2 < n) v2 = cnt[i0 + 2];
      if (i0 + 3 < n) v3 = cnt[i0 + 3];
    }
    int tsum = v0 + v1 + v2 + v3;
    int s = tsum;
    #pragma unroll
    for (int off = 1; off < 64; off <<= 1){
      int t = __shfl_up(s, off, 64);
      if (lane >= off) s += t;
    }
    if (lane == 63) wsums[wv] = s;
    __syncthreads();
    if (wv == 0 && lane < 16){
      int t = wsums[lane];
      #pragma unroll
      for (int off = 1; off < 16; off <<= 1){
        int u = __shfl_up(t, off, 64);
        if (lane >= off) t += u;
      }
      wsums[lane] = t;
    }
    __syncthreads();
    int woff  = (wv == 0) ? 0 : wsums[wv - 1];
    int total = wsums[15];
    int excl = carry + woff + s - tsum;
    if (i0 + 3 < n){
      int4 w;
      w.x = excl; w.y = excl + v0; w.z = excl + v0 + v1; w.w = excl + v0 + v1 + v2;
      *(int4*)(rowptr + i0) = w;
    } else {
      if (i0     < n) rowptr[i0]     = excl;
      if (i0 + 1 < n) rowptr[i0 + 1] = excl + v0;
      if (i0 + 2 < n) rowptr[i0 + 2] = excl + v0 + v1;
      if (i0 + 3 < n) rowptr[i0 + 3] = excl + v0 + v1 + v2;
    }
    __syncthreads();
    carry += total;
  }
  if (tid == 0) rowptr[n] = carry;
}

// ---------------- bucketed CSR build (no global atomics, line-local writes) ------------
// buckets of 256 consecutive targets; P edge chunks.
#define CSR_P 256

// A1: per-chunk bucket histogram -> counts[bucket*P + block]
__global__ __launch_bounds__(256) void bucket_hist(const int* __restrict__ tgt, int E,
                                                   int chunk, int NB, int* __restrict__ counts){
  __shared__ int hist[256];
  for (int i = threadIdx.x; i < NB; i += 256) hist[i] = 0;
  __syncthreads();
  int b0 = blockIdx.x * chunk, b1 = min(b0 + chunk, E);
  for (int e = b0 + threadIdx.x; e < b1; e += 256)
    atomicAdd(&hist[tgt[e] >> 8], 1);
  __syncthreads();
  for (int i = threadIdx.x; i < NB; i += 256)
    counts[i * CSR_P + blockIdx.x] = hist[i];
}

// A3: append (src,tgt) pairs into per-(bucket,block) slices given by offs
__global__ __launch_bounds__(256) void bucket_scatter(const int* __restrict__ tgt,
                                                      const int* __restrict__ src, int E,
                                                      int chunk, int NB,
                                                      const int* __restrict__ offs,
                                                      int2* __restrict__ pairs){
  __shared__ int cur[256];
  for (int i = threadIdx.x; i < NB; i += 256) cur[i] = offs[i * CSR_P + blockIdx.x];
  __syncthreads();
  int b0 = blockIdx.x * chunk, b1 = min(b0 + chunk, E);
  for (int e = b0 + threadIdx.x; e < b1; e += 256){
    int t = tgt[e];
    int pos = atomicAdd(&cur[t >> 8], 1);
    pairs[pos] = make_int2(src[e], t);
  }
}

// B: one block per bucket -> rowptr + col
__global__ __launch_bounds__(1024) void bucket_build(const int* __restrict__ offs, int NB,
                                                     int n_tgt, const int2* __restrict__ pairs,
                                                     int* __restrict__ rowptr,
                                                     int* __restrict__ col){
  __shared__ int hist[256];
  __shared__ int excl[256];
  __shared__ int cur[256];
  int b = blockIdx.x;
  int tid = threadIdx.x;
  int start = offs[b * CSR_P];
  int end   = offs[(b + 1) * CSR_P];
  for (int i = tid; i < 256; i += 1024) hist[i] = 0;
  __syncthreads();
  for (int e = start + tid; e < end; e += 1024)
    atomicAdd(&hist[pairs[e].y & 255], 1);
  __syncthreads();
  if (tid < 64){
    int lane = tid;
    int a0 = hist[4 * lane], a1 = hist[4 * lane + 1], a2 = hist[4 * lane + 2], a3 = hist[4 * lane + 3];
    int tsum = a0 + a1 + a2 + a3;
    int s = tsum;
    #pragma unroll
    for (int off = 1; off < 64; off <<= 1){
      int t = __shfl_up(s, off, 64);
      if (lane >= off) s += t;
    }
    int e0 = s - tsum;
    excl[4 * lane]     = e0;
    excl[4 * lane + 1] = e0 + a0;
    excl[4 * lane + 2] = e0 + a0 + a1;
    excl[4 * lane + 3] = e0 + a0 + a1 + a2;
  }
  __syncthreads();
  int t0 = b << 8;
  int valid = min(256, n_tgt - t0);
  for (int i = tid; i < valid; i += 1024) rowptr[t0 + i] = start + excl[i];
  if (b == NB - 1 && tid == 0) rowptr[n_tgt] = offs[NB * CSR_P];
  for (int i = tid; i < 256; i += 1024) cur[i] = excl[i];
  __syncthreads();
  for (int e = start + tid; e < end; e += 1024){
    int2 p = pairs[e];
    int pos = atomicAdd(&cur[p.y & 255], 1);
    col[start + pos] = p.x;
  }
}

// ---------------- softmax-aggregate + (+Qw) + LN0 : one wave per target ----------------
__global__ __launch_bounds__(256) void agg_kernel(const int* __restrict__ rowptr,
                                                  const int* __restrict__ col,
                                                  const float* __restrict__ logits,
                                                  const unsigned short* __restrict__ xV,
                                                  const float* __restrict__ qvec,
                                                  const float* __restrict__ g0,
                                                  const float* __restrict__ b0,
                                                  float* __restrict__ h_out,
                                                  unsigned short* __restrict__ hb_out,
                                                  int n_tgt){
  int wid = (blockIdx.x << 2) + (threadIdx.x >> 6);
  if (wid >= n_tgt) return;
  int lane = threadIdx.x & 63;
  int head = lane >> 4;
  int beg = rowptr[wid];
  int k   = rowptr[wid + 1] - beg;

  float mx0 = -INFINITY, mx1 = -INFINITY, mx2 = -INFINITY, mx3 = -INFINITY;
  for (int i = lane; i < k; i += 64){
    int s = col[beg + i];
    float4 a = *(const float4*)(logits + 4 * (size_t)s);
    mx0 = fmaxf(mx0, a.x); mx1 = fmaxf(mx1, a.y);
    mx2 = fmaxf(mx2, a.z); mx3 = fmaxf(mx3, a.w);
  }
  mx0 = wmax64(mx0); mx1 = wmax64(mx1); mx2 = wmax64(mx2); mx3 = wmax64(mx3);
  float mymax = (head == 0) ? mx0 : (head == 1) ? mx1 : (head == 2) ? mx2 : mx3;

  float accx = 0.f, accy = 0.f, sumw = 0.f;
  #pragma unroll 4
  for (int e = 0; e < k; ++e){
    int se = col[beg + e];
    float a = logits[4 * (size_t)se + head];
    float w = __expf(a - mymax);
    sumw += w;
    unsigned int v = *(const unsigned int*)(xV + 128 * (size_t)se + 2 * lane);
    accx += w * bf2f((unsigned short)(v & 0xffffu));
    accy += w * bf2f((unsigned short)(v >> 16));
  }
  float inv = (k > 0) ? 1.f / sumw : 0.f;
  accx *= inv; accy *= inv;

  float2 q = *(const float2*)(qvec + 2 * lane);
  accx += q.x; accy += q.y;

  float mean = wsum64(accx + accy) * (1.f / 128.f);
  float dx = accx - mean, dy = accy - mean;
  float var = wsum64(dx * dx + dy * dy) * (1.f / 128.f);
  float rstd = rsqrtf(var + 1e-5f);
  float2 g = *(const float2*)(g0 + 2 * lane);
  float2 b = *(const float2*)(b0 + 2 * lane);
  float ox = dx * rstd * g.x + b.x;
  float oy = dy * rstd * g.y + b.y;
  *(float2*)(h_out + 128 * (size_t)wid + 2 * lane) = make_float2(ox, oy);
  unsigned int pk = ((unsigned int)f2bf(oy) << 16) | (unsigned int)f2bf(ox);
  *(unsigned int*)(hb_out + 128 * (size_t)wid + 2 * lane) = pk;
}

// ---------------- bf16 MFMA GEMM: C[R,128] = act(A[R,128] @ B[128,128]) ----------------
template<bool A_BF16, bool OUT_BF16, bool RELU>
__global__ __launch_bounds__(256) void mfma_gemm128(const void* __restrict__ Ap,
                                                    const unsigned short* __restrict__ Bt,
                                                    void* __restrict__ Cp, int R){
  __shared__ unsigned short As[64 * 136];
  __shared__ unsigned short Bs[128 * 136];
  int tid = threadIdx.x;
  int row0 = blockIdx.x * 64;

  #pragma unroll
  for (int i = 0; i < 16; ++i){
    int f = tid + i * 256;
    int n = f >> 5, c4 = f & 31;
    *(ushort4*)&Bs[n * 136 + c4 * 4] = *(const ushort4*)(Bt + n * 128 + c4 * 4);
  }
  if (A_BF16){
    const unsigned short* A = (const unsigned short*)Ap;
    #pragma unroll
    for (int i = 0; i < 8; ++i){
      int f = tid + i * 256;
      int r = f >> 5, c4 = f & 31;
      ushort4 v = make_ushort4(0, 0, 0, 0);
      if (row0 + r < R) v = *(const ushort4*)(A + (size_t)(row0 + r) * 128 + c4 * 4);
      *(ushort4*)&As[r * 136 + c4 * 4] = v;
    }
  } else {
    const float* A = (const float*)Ap;
    #pragma unroll
    for (int i = 0; i < 8; ++i){
      int f = tid + i * 256;
      int r = f >> 5, c4 = f & 31;
      float4 v = make_float4(0.f, 0.f, 0.f, 0.f);
      if (row0 + r < R) v = *(const float4*)(A + (size_t)(row0 + r) * 128 + c4 * 4);
      ushort4 h;
      h.x = f2bf(v.x); h.y = f2bf(v.y); h.z = f2bf(v.z); h.w = f2bf(v.w);
      *(ushort4*)&As[r * 136 + c4 * 4] = h;
    }
  }
  __syncthreads();

  int lane = tid & 63, wv = tid >> 6;
  int m = lane & 15, quad = lane >> 4;
  f32x4 acc[8];
  #pragma unroll
  for (int j = 0; j < 8; ++j) acc[j] = (f32x4){0.f, 0.f, 0.f, 0.f};

  #pragma unroll
  for (int q = 0; q < 4; ++q){
    bf16x8 a = *(const bf16x8*)&As[(wv * 16 + m) * 136 + q * 32 + quad * 8];
    #pragma unroll
    for (int j = 0; j < 8; ++j){
      bf16x8 b = *(const bf16x8*)&Bs[(j * 16 + m) * 136 + q * 32 + quad * 8];
      acc[j] = __builtin_amdgcn_mfma_f32_16x16x32_bf16(a, b, acc[j], 0, 0, 0);
    }
  }

  #pragma unroll
  for (int j = 0; j < 8; ++j){
    int colc = j * 16 + m;
    #pragma unroll
    for (int r = 0; r < 4; ++r){
      int gr = row0 + wv * 16 + quad * 4 + r;
      if (gr < R){
        float v = acc[j][r];
        if (RELU) v = fmaxf(v, 0.f);
        if (OUT_BF16) ((unsigned short*)Cp)[(size_t)gr * 128 + colc] = f2bf(v);
        else          ((float*)Cp)[(size_t)gr * 128 + colc] = v;
      }
    }
  }
}

// ---------------- out = relu(LN(h + m)) : one wave per row ----------------
__global__ __launch_bounds__(256) void final_ln_kernel(const float* __restrict__ h,
                                                       const float* __restrict__ m,
                                                       const float* __restrict__ g,
                                                       const float* __restrict__ b,
                                                       float* __restrict__ out, int R){
  int row = (blockIdx.x << 2) + (threadIdx.x >> 6);
  if (row >= R) return;
  int lane = threadIdx.x & 63;
  float2 hv = *(const float2*)(h + 128 * (size_t)row + 2 * lane);
  float2 mv = *(const float2*)(m + 128 * (size_t)row + 2 * lane);
  float vx = hv.x + mv.x, vy = hv.y + mv.y;
  float mean = wsum64(vx + vy) * (1.f / 128.f);
  float dx = vx - mean, dy = vy - mean;
  float var = wsum64(dx * dx + dy * dy) * (1.f / 128.f);
  float rstd = rsqrtf(var + 1e-5f);
  float2 gg = *(const float2*)(g + 2 * lane);
  float2 bb = *(const float2*)(b + 2 * lane);
  float ox = fmaxf(dx * rstd * gg.x + bb.x, 0.f);
  float oy = fmaxf(dy * rstd * gg.y + bb.y, 0.f);
  *(float2*)(out + 128 * (size_t)row + 2 * lane) = make_float2(ox, oy);
}

// ---------------- host side ----------------
struct Ws {
  float *kq, *logits, *h, *m;
  unsigned short *btV, *btW1, *btW2, *xv, *hb;
  int2* pairs;            // aliases xv region
  int *counts, *offs;     // aliases xv region (after pairs)
};

static void build_csr(const int* tgt, const int* src, int E, int n_tgt,
                      int* rowptr, int* col, const Ws& ws, hipStream_t stream){
  int NB = (n_tgt + 255) >> 8;
  int chunk = (E + CSR_P - 1) / CSR_P;
  bucket_hist<<<CSR_P, 256, 0, stream>>>(tgt, E, chunk, NB, ws.counts);
  scan_kernel<<<1, 1024, 0, stream>>>(ws.counts, ws.offs, NB * CSR_P);
  bucket_scatter<<<CSR_P, 256, 0, stream>>>(tgt, src, E, chunk, NB, ws.offs, ws.pairs);
  bucket_build<<<NB, 1024, 0, stream>>>(ws.offs, NB, n_tgt, ws.pairs, rowptr, col);
}

static void run_stage(const float* x, int R_src,
                      const int* rowptr, const int* col, int n_tgt,
                      const float* K, const float* Qw, const float* V,
                      const float* g0, const float* b0,
                      const float* W1, const float* W2,
                      const float* g1, const float* b1,
                      float* out, const Ws& ws, hipStream_t stream)
{
  kq_kernel<<<1, 512, 0, stream>>>(K, Qw, ws.kq);
  btv_kernel<<<64, 256, 0, stream>>>(V, ws.btV);
  btw_kernel<<<64, 256, 0, stream>>>(W1, ws.btW1);
  btw_kernel<<<64, 256, 0, stream>>>(W2, ws.btW2);
  logits_kernel<<<(R_src + 3) / 4, 256, 0, stream>>>(x, ws.kq, ws.logits, R_src);
  mfma_gemm128<false, true, false><<<(R_src + 63) / 64, 256, 0, stream>>>(x, ws.btV, ws.xv, R_src);

  agg_kernel<<<(n_tgt + 3) / 4, 256, 0, stream>>>(rowptr, col, ws.logits, ws.xv,
                                                  Qw, g0, b0, ws.h, ws.hb, n_tgt);
  mfma_gemm128<true, true, true><<<(n_tgt + 63) / 64, 256, 0, stream>>>(ws.hb, ws.btW1, ws.xv, n_tgt);
  mfma_gemm128<true, false, true><<<(n_tgt + 63) / 64, 256, 0, stream>>>(ws.xv, ws.btW2, ws.m, n_tgt);
  final_ln_kernel<<<(n_tgt + 3) / 4, 256, 0, stream>>>(ws.h, ws.m, g1, b1, out, n_tgt);
}

extern "C" void kernel_launch(void* const* d_in, const int* in_sizes, int n_in,
                              void* d_out, int out_size, void* d_ws, size_t ws_size,
                              hipStream_t stream)
{
  const float* x0        = (const float*)d_in[0];
  const int*   node_idx  = (const int*)d_in[1];
  const int*   hedge_idx = (const int*)d_in[2];
  const float* v2e_K = (const float*)d_in[5];
  const float* v2e_Q = (const float*)d_in[6];
  const float* v2e_V = (const float*)d_in[7];
  const float* v2e_g0 = (const float*)d_in[8];
  const float* v2e_b0 = (const float*)d_in[9];
  const float* v2e_W1 = (const float*)d_in[10];
  const float* v2e_W2 = (const float*)d_in[11];
  const float* v2e_g1 = (const float*)d_in[12];
  const float* v2e_b1 = (const float*)d_in[13];
  const float* e2v_K = (const float*)d_in[14];
  const float* e2v_Q = (const float*)d_in[15];
  const float* e2v_V = (const float*)d_in[16];
  const float* e2v_g0 = (const float*)d_in[17];
  const float* e2v_b0 = (const float*)d_in[18];
  const float* e2v_W1 = (const float*)d_in[19];
  const float* e2v_W2 = (const float*)d_in[20];
  const float* e2v_g1 = (const float*)d_in[21];
  const float* e2v_b1 = (const float*)d_in[22];

  int N = in_sizes[0] / 128;          // 50000
  int E = in_sizes[1];                // 1000000
  int M = out_size / 128 - N;         // 20000

  float* out_x0 = (float*)d_out;
  float* out_x1 = (float*)d_out + (size_t)N * 128;

  size_t off = 0;
  char* base = (char*)d_ws;
  auto alloc = [&](size_t bytes) -> void* {
    void* p = base + off;
    off += (bytes + 255) & ~(size_t)255;
    return p;
  };
  Ws ws;
  ws.kq     = (float*)alloc(512 * 4);
  ws.btV    = (unsigned short*)alloc(16384 * 2);
  ws.btW1   = (unsigned short*)alloc(16384 * 2);
  ws.btW2   = (unsigned short*)alloc(16384 * 2);
  ws.logits = (float*)alloc((size_t)N * 4 * 4);
  // union region: {pairs, counts, offs} during CSR builds; xv afterwards
  size_t uoff = off;
  ws.xv     = (unsigned short*)alloc((size_t)N * 128 * 2);   // 12.8 MB
  ws.pairs  = (int2*)(base + uoff);                          // 8 MB
  ws.counts = (int*)(base + uoff + (size_t)E * 8);           // 256 KB
  ws.offs   = (int*)(base + uoff + (size_t)E * 8 + 256 * CSR_P * 4 + 256);
  ws.hb     = (unsigned short*)alloc((size_t)N * 128 * 2);
  ws.h      = (float*)alloc((size_t)N * 128 * 4);
  ws.m      = (float*)alloc((size_t)N * 128 * 4);
  int* rowptr0 = (int*)alloc(((size_t)M + 1) * 4);
  int* col0    = (int*)alloc((size_t)E * 4);
  int* rowptr1 = (int*)alloc(((size_t)N + 1) * 4);
  int* col1    = (int*)alloc((size_t)E * 4);
  (void)ws_size; (void)n_in;

  // CSR builds up front (input-only; pairs/counts/offs alias xv which is not yet live)
  build_csr(hedge_idx, node_idx, E, M, rowptr0, col0, ws, stream);   // stage 1: by hyperedge
  build_csr(node_idx, hedge_idx, E, N, rowptr1, col1, ws, stream);   // stage 2: by node

  // stage 1: vertex -> hyperedge, out = x_1
  run_stage(x0, N, rowptr0, col0, M,
            v2e_K, v2e_Q, v2e_V, v2e_g0, v2e_b0, v2e_W1, v2e_W2, v2e_g1, v2e_b1,
            out_x1, ws, stream);

  // stage 2: hyperedge -> vertex, out = x_0_out
  run_stage(out_x1, M, rowptr1, col1, N,
            e2v_K, e2v_Q, e2v_V, e2v_g0, e2v_b0, e2v_W1, e2v_W2, e2v_g1, e2v_b1,
            out_x0, ws, stream);
}